// Round 3
// baseline (1231.258 us; speedup 1.0000x reference)
//
#include <hip/hip_runtime.h>
#include <hip/hip_bf16.h>

typedef __hip_bfloat16 bf16;
typedef __attribute__((ext_vector_type(8))) short short8;
typedef __attribute__((ext_vector_type(4))) float floatx4;

struct bf16x4 { bf16 a, b, c, d; };  // 8-byte packed store unit

// ---- problem constants ----
// B=2, S=4096, T=8192 tokens
// out shape (2, 96, 4096, 192) fp32: b-stride 75497472, head-stride 786432
#define OUT_BSTRIDE 75497472u
#define OUT_HSTRIDE 786432u

__device__ __forceinline__ void gload_lds16(const bf16* g, bf16* l) {
    __builtin_amdgcn_global_load_lds((const __attribute__((address_space(1))) void*)g,
                                     (__attribute__((address_space(3))) void*)l,
                                     16, 0, 0);
}

// ---------------------------------------------------------------------------
// fp32 -> bf16 conversion, grid-stride, float4 in / 8B out. n % 4 == 0.
// ---------------------------------------------------------------------------
__global__ __launch_bounds__(256) void cvt_f32_bf16(const float* __restrict__ src,
                                                    bf16* __restrict__ dst, int n4) {
    const int stride = gridDim.x * blockDim.x;
    for (int i = blockIdx.x * blockDim.x + threadIdx.x; i < n4; i += stride) {
        const float4 v = ((const float4*)src)[i];
        bf16x4 o;
        o.a = __float2bfloat16(v.x);
        o.b = __float2bfloat16(v.y);
        o.c = __float2bfloat16(v.z);
        o.d = __float2bfloat16(v.w);
        ((bf16x4*)dst)[i] = o;
    }
}

// ---------------------------------------------------------------------------
// 128x128 tile bf16 GEMM, C = A * B^T (A: MxK row-major, B: NxK row-major).
// MODE 0: A=hidden_bf(K=4096). grid.y<12 -> B=q_a_w (N=1536) -> Cq bf16
//         grid.y>=12 -> B=kv_a_w (N=576, clamp+mask) -> Ckv bf16
// MODE 1: A=q_a_norm (K=1536), B=q_b_w -> Of fp32, q layout + pe permute
// MODE 2: A=ckv_norm (lda=576, K=512), B=kv_b_w -> Of fp32, k_nope/value layout
// ---------------------------------------------------------------------------
template <int MODE>
__global__ __launch_bounds__(256) void gemm_bt(const bf16* __restrict__ A,
                                               const bf16* __restrict__ Bq,
                                               const bf16* __restrict__ Bkv,
                                               bf16* __restrict__ Cq,
                                               bf16* __restrict__ Ckv,
                                               float* __restrict__ Of) {
    constexpr int K   = (MODE == 0) ? 4096 : (MODE == 1) ? 1536 : 512;
    constexpr int LDA = (MODE == 0) ? 4096 : (MODE == 1) ? 1536 : 576;
    constexpr int LDB = (MODE == 0) ? 4096 : (MODE == 1) ? 1536 : 512;

    __shared__ __align__(16) bf16 sA[128 * 32];
    __shared__ __align__(16) bf16 sB[128 * 32];

    const int tid = threadIdx.x;
    const int m0  = blockIdx.x * 128;

    const bf16* Bsel;
    bf16* Cbf = nullptr;
    int n0, nmax = 0x40000000, ldc = 0;
    if constexpr (MODE == 0) {
        if (blockIdx.y < 12) {
            Bsel = Bq;  n0 = blockIdx.y * 128;        nmax = 1536; ldc = 1536; Cbf = Cq;
        } else {
            Bsel = Bkv; n0 = (blockIdx.y - 12) * 128; nmax = 576;  ldc = 576;  Cbf = Ckv;
        }
    } else {
        Bsel = Bq; n0 = blockIdx.y * 128;
    }

    // ---- staging addresses (global per-lane, LDS dest = wave-uniform + lane*16B) ----
    const int r0 = tid >> 2;        // row 0..63
    const int kc = tid & 3;         // 8-elem k-chunk 0..3
    const bf16* ga0 = A + (size_t)(m0 + r0) * LDA + kc * 8;
    const bf16* ga1 = ga0 + (size_t)64 * LDA;
    int br0 = n0 + r0;      if (br0 > nmax - 1) br0 = nmax - 1;
    int br1 = n0 + r0 + 64; if (br1 > nmax - 1) br1 = nmax - 1;
    const bf16* gb0 = Bsel + (size_t)br0 * LDB + kc * 8;
    const bf16* gb1 = Bsel + (size_t)br1 * LDB + kc * 8;
    bf16* lA0 = sA + tid * 8;
    bf16* lA1 = sA + (tid + 256) * 8;
    bf16* lB0 = sB + tid * 8;
    bf16* lB1 = sB + (tid + 256) * 8;

    // ---- fragment addresses ----
    const int lane = tid & 63;
    const int wid  = tid >> 6;
    const int wm   = wid >> 1;      // 2x2 wave grid, 64x64 per wave
    const int wn   = wid & 1;
    const int ln   = lane & 15;
    const int qo   = (lane >> 4) * 8;

    const short8* pa[4];
    const short8* pb[4];
#pragma unroll
    for (int i = 0; i < 4; ++i) {
        pa[i] = (const short8*)(sA + (wm * 64 + i * 16 + ln) * 32 + qo);
        pb[i] = (const short8*)(sB + (wn * 64 + i * 16 + ln) * 32 + qo);
    }

    floatx4 acc[4][4];
#pragma unroll
    for (int i = 0; i < 4; ++i)
#pragma unroll
        for (int j = 0; j < 4; ++j) acc[i][j] = (floatx4){0.f, 0.f, 0.f, 0.f};

    for (int k0 = 0; k0 < K; k0 += 32) {
        gload_lds16(ga0, lA0);
        gload_lds16(ga1, lA1);
        gload_lds16(gb0, lB0);
        gload_lds16(gb1, lB1);
        ga0 += 32; ga1 += 32; gb0 += 32; gb1 += 32;
        __syncthreads();

        short8 af[4], bfr[4];
#pragma unroll
        for (int i = 0; i < 4; ++i) af[i] = *pa[i];
#pragma unroll
        for (int j = 0; j < 4; ++j) bfr[j] = *pb[j];
#pragma unroll
        for (int i = 0; i < 4; ++i)
#pragma unroll
            for (int j = 0; j < 4; ++j)
                acc[i][j] = __builtin_amdgcn_mfma_f32_16x16x32_bf16(af[i], bfr[j], acc[i][j], 0, 0, 0);
        __syncthreads();
    }

    // ---- epilogue ----  C/D: row = (lane>>4)*4 + reg, col = lane&15
    const int rowq = (lane >> 4) * 4;
#pragma unroll
    for (int j = 0; j < 4; ++j) {
        const int c0 = n0 + wn * 64 + j * 16;  // tile-uniform column base
        const int c  = c0 + ln;

        if constexpr (MODE == 0) {
            const bool ok = (c < nmax);
#pragma unroll
            for (int i = 0; i < 4; ++i) {
                const int t = m0 + wm * 64 + i * 16 + rowq;
#pragma unroll
                for (int r = 0; r < 4; ++r) {
                    if (ok) Cbf[(size_t)(t + r) * ldc + c] = __float2bfloat16(acc[i][j][r]);
                }
            }
        } else {
            size_t colbase;
            if constexpr (MODE == 1) {
                // q: col = h*192 + e ; e<128 direct, else deepseek pe permute
                const int h  = c0 / 192;          // tile-uniform (192 = 12*16)
                const int e0 = c0 - h * 192;
                const int e  = e0 + ln;
                int d;
                if (e0 >= 128) {
                    const int p = e - 128;
                    d = 128 + (p & 1) * 32 + (p >> 1);
                } else {
                    d = e;
                }
                colbase = (size_t)h * OUT_HSTRIDE + d;
            } else {
                // kv: col = h*256 + e ; e<128 -> k_nope (head 32+h), else value (head 64+h)
                const int h  = c0 >> 8;
                const int e0 = c0 & 255;
                const int e  = e0 + ln;
                const int head = (e0 < 128) ? (32 + h) : (64 + h);
                const int d    = (e0 < 128) ? e : (e - 128);
                colbase = (size_t)head * OUT_HSTRIDE + d;
            }
#pragma unroll
            for (int i = 0; i < 4; ++i) {
                const int tbase = m0 + wm * 64 + i * 16 + rowq;
#pragma unroll
                for (int r = 0; r < 4; ++r) {
                    const int t  = tbase + r;
                    const int bb = t >> 12;
                    const int ss = t & 4095;
                    Of[(size_t)bb * OUT_BSTRIDE + (size_t)ss * 192 + colbase] = acc[i][j][r];
                }
            }
        }
    }
}

// ---------------------------------------------------------------------------
// RMSNorm (in-place on bf16 ws) + k_pe deepseek-transpose broadcast (fp32 out)
// + value zero-pad (fp32 out).
// blocks [0,8192): q_a rows (1536). blocks [8192,16384): ckv rows (norm first
// 512; cols 512..575 = k_pe -> heads 32..63 d 128..191; zeros heads 64..95).
// ---------------------------------------------------------------------------
__global__ __launch_bounds__(256) void norm_kpe(bf16* __restrict__ q_a,
                                                bf16* __restrict__ ckv,
                                                const float* __restrict__ qw,
                                                const float* __restrict__ kw,
                                                float* __restrict__ out) {
    __shared__ float red[4];
    __shared__ float skpe[64];
    const int tid = threadIdx.x;
    const int r   = blockIdx.x;

    if (r < 8192) {
        bf16* row = q_a + (size_t)r * 1536;
        float x[6];
#pragma unroll
        for (int k = 0; k < 6; ++k) x[k] = __bfloat162float(row[tid + k * 256]);
        float ss = 0.f;
#pragma unroll
        for (int k = 0; k < 6; ++k) ss += x[k] * x[k];
#pragma unroll
        for (int o = 32; o > 0; o >>= 1) ss += __shfl_down(ss, o, 64);
        if ((tid & 63) == 0) red[tid >> 6] = ss;
        __syncthreads();
        const float tot   = red[0] + red[1] + red[2] + red[3];
        const float scale = rsqrtf(tot * (1.0f / 1536.0f) + 1e-6f);
#pragma unroll
        for (int k = 0; k < 6; ++k) {
            const float w = qw[tid + k * 256];
            row[tid + k * 256] = __float2bfloat16(x[k] * scale * w);
        }
    } else {
        const int t = r - 8192;
        bf16* row   = ckv + (size_t)t * 576;
        float x0 = __bfloat162float(row[tid]);
        float x1 = __bfloat162float(row[tid + 256]);
        if (tid < 64) skpe[tid] = __bfloat162float(row[512 + tid]);
        float ss = x0 * x0 + x1 * x1;
#pragma unroll
        for (int o = 32; o > 0; o >>= 1) ss += __shfl_down(ss, o, 64);
        if ((tid & 63) == 0) red[tid >> 6] = ss;
        __syncthreads();
        const float tot   = red[0] + red[1] + red[2] + red[3];
        const float scale = rsqrtf(tot * (1.0f / 512.0f) + 1e-6f);
        row[tid]       = __float2bfloat16(x0 * scale * kw[tid]);
        row[tid + 256] = __float2bfloat16(x1 * scale * kw[tid + 256]);

        // k_pe broadcast + value pad. dest d=128+i; source = kpe[2*(i&31)+(i>>5)]
        const int i  = tid & 63;
        const int hg = tid >> 6;  // 4 head groups of 8
        const float v = skpe[2 * (i & 31) + (i >> 5)];
        const int bb  = t >> 12;
        const int ssx = t & 4095;
        float* obase = out + (size_t)bb * OUT_BSTRIDE + (size_t)ssx * 192 + 128 + i;
#pragma unroll
        for (int h = 0; h < 8; ++h) {
            const int head = hg * 8 + h;  // 0..31
            obase[(size_t)(32 + head) * OUT_HSTRIDE] = v;     // key pe
            obase[(size_t)(64 + head) * OUT_HSTRIDE] = 0.0f;  // value pad
        }
    }
}

extern "C" void kernel_launch(void* const* d_in, const int* in_sizes, int n_in,
                              void* d_out, int out_size, void* d_ws, size_t ws_size,
                              hipStream_t stream) {
    const float* hidden = (const float*)d_in[0];   // 8192 x 4096
    const float* q_a_w  = (const float*)d_in[1];   // 1536 x 4096
    const float* q_b_w  = (const float*)d_in[2];   // 6144 x 1536
    const float* kv_a_w = (const float*)d_in[3];   // 576  x 4096
    const float* kv_b_w = (const float*)d_in[4];   // 8192 x 512
    const float* q_ln   = (const float*)d_in[5];   // 1536
    const float* kv_ln  = (const float*)d_in[6];   // 512
    float* out = (float*)d_out;

    // ---- workspace layout (bf16), ~146 MB ----
    bf16* hid_b  = (bf16*)d_ws;                          // 33.55M el
    bf16* qaw_b  = hid_b + (size_t)8192 * 4096;          //  6.29M
    bf16* qbw_b  = qaw_b + (size_t)1536 * 4096;          //  9.44M
    bf16* kvaw_b = qbw_b + (size_t)6144 * 1536;          //  2.36M
    bf16* kvbw_b = kvaw_b + (size_t)576 * 4096;          //  4.19M
    bf16* q_a    = kvbw_b + (size_t)8192 * 512;          // 12.58M
    bf16* ckv    = q_a + (size_t)8192 * 1536;            //  4.72M

    dim3 blk(256);
    // ---- fp32 -> bf16 converts (memory-bound) ----
    cvt_f32_bf16<<<dim3(4096), blk, 0, stream>>>(hidden, hid_b, 8192 * 4096 / 4);
    cvt_f32_bf16<<<dim3(1024), blk, 0, stream>>>(q_a_w, qaw_b, 1536 * 4096 / 4);
    cvt_f32_bf16<<<dim3(1024), blk, 0, stream>>>(q_b_w, qbw_b, 6144 * 1536 / 4);
    cvt_f32_bf16<<<dim3(512),  blk, 0, stream>>>(kv_a_w, kvaw_b, 576 * 4096 / 4);
    cvt_f32_bf16<<<dim3(512),  blk, 0, stream>>>(kv_b_w, kvbw_b, 8192 * 512 / 4);

    // K1: fused a-projections (q_a + ckv)
    gemm_bt<0><<<dim3(64, 17), blk, 0, stream>>>(hid_b, qaw_b, kvaw_b, q_a, ckv, nullptr);
    // K2: rmsnorms in-place + k_pe broadcast + value pad
    norm_kpe<<<dim3(16384), blk, 0, stream>>>(q_a, ckv, q_ln, kv_ln, out);
    // K3: q projection -> out heads 0..31
    gemm_bt<1><<<dim3(64, 48), blk, 0, stream>>>(q_a, qbw_b, nullptr, nullptr, nullptr, out);
    // K4: kv projection -> out heads 32..95
    gemm_bt<2><<<dim3(64, 64), blk, 0, stream>>>(ckv, kvbw_b, nullptr, nullptr, nullptr, out);
}